// Round 1
// baseline (737.646 us; speedup 1.0000x reference)
//
#include <hip/hip_runtime.h>
#include <hip/hip_bf16.h>

#define NHD 8
#define HD  32
#define C_  256
#define TD_ 512
#define S_  256
#define N_  32768   // D*H*W = 32*32*32
#define B_  2

// ---------------------------------------------------------------------------
// Kernel 1: text stage — k = text@k_w+k_b, v = text@v_w+v_b,
// h = gelu(text@m1_w+m1_b), phase = h@m2_w+m2_b, k_rot = rope(k, phase).
// Outputs k_rot, v in [B][NH][S][HD] layout. 4 tokens per block.
// ---------------------------------------------------------------------------
__global__ __launch_bounds__(256) void text_stage(
    const float* __restrict__ text,
    const float* __restrict__ k_w, const float* __restrict__ k_b,
    const float* __restrict__ v_w, const float* __restrict__ v_b,
    const float* __restrict__ m1_w, const float* __restrict__ m1_b,
    const float* __restrict__ m2_w, const float* __restrict__ m2_b,
    float* __restrict__ k_rot, float* __restrict__ v_out)
{
    __shared__ float t_s[4][TD_];   // 8 KB
    __shared__ float h_s[4][C_];    // 4 KB
    __shared__ float k_s[4][C_];    // 4 KB
    const int tid = threadIdx.x;
    const int token0 = blockIdx.x * 4;   // grid = 128

    for (int i = tid; i < 4 * TD_; i += 256)
        t_s[i >> 9][i & (TD_ - 1)] = text[(size_t)token0 * TD_ + i];
    __syncthreads();

    float kv[4], vv[4], hv[4];
#pragma unroll
    for (int tk = 0; tk < 4; ++tk) { kv[tk] = k_b[tid]; vv[tk] = v_b[tid]; hv[tk] = m1_b[tid]; }

    for (int j = 0; j < TD_; ++j) {
        float wk = k_w[j * C_ + tid];
        float wv = v_w[j * C_ + tid];
        float wm = m1_w[j * C_ + tid];
#pragma unroll
        for (int tk = 0; tk < 4; ++tk) {
            float tj = t_s[tk][j];
            kv[tk] += tj * wk; vv[tk] += tj * wv; hv[tk] += tj * wm;
        }
    }
#pragma unroll
    for (int tk = 0; tk < 4; ++tk) {
        float h = hv[tk];
        h = 0.5f * h * (1.0f + erff(h * 0.70710678118654752f));  // exact GELU
        h_s[tk][tid] = h;
        k_s[tk][tid] = kv[tk];
    }
    __syncthreads();

    float ph[4];
#pragma unroll
    for (int tk = 0; tk < 4; ++tk) ph[tk] = m2_b[tid];
    for (int j = 0; j < C_; ++j) {
        float wm = m2_w[j * C_ + tid];
#pragma unroll
        for (int tk = 0; tk < 4; ++tk) ph[tk] += h_s[tk][j] * wm;
    }

    const int t = tid & (HD - 1);
    const int nh = tid >> 5;
#pragma unroll
    for (int tk = 0; tk < 4; ++tk) {
        int token = token0 + tk;
        int b = token >> 8, s = token & (S_ - 1);
        float partner = (t < 16) ? -k_s[tk][tid + 16] : k_s[tk][tid - 16];
        float kr = kv[tk] * cosf(ph[tk]) + partner * sinf(ph[tk]);
        size_t o = ((size_t)(b * NHD + nh) * S_ + s) * HD + t;
        k_rot[o] = kr;
        v_out[o] = vv[tk];
    }
}

// ---------------------------------------------------------------------------
// Kernel 2: Q projection GEMM + fused 3D-RoPE epilogue.
// A = fused_visual[b] viewed [C][N] (K-major, n contiguous), B = q_w [C][C].
// Output q_rot [B][NH][N][HD].
// 64n x 64co tile per block, 256 threads (16x16), 4x4 micro-tile.
// ---------------------------------------------------------------------------
__global__ __launch_bounds__(256) void qproj_rope(
    const float* __restrict__ fv,   // [B][C][N]
    const float* __restrict__ q_w, const float* __restrict__ q_b,
    float* __restrict__ q_rot)
{
    __shared__ float As[16][64];
    __shared__ float Bs[16][64];
    __shared__ float qs[64][68];    // +4 pad

    const int tid = threadIdx.x;
    const int tn = tid & 15, tc = tid >> 4;
    const int n0 = blockIdx.x * 64, c0 = blockIdx.y * 64, b = blockIdx.z;
    const float* Ab = fv + (size_t)b * C_ * N_;
    const int lrow = tid >> 4, lcol = (tid & 15) * 4;

    float acc[4][4] = {};
    for (int kc = 0; kc < C_; kc += 16) {
        __syncthreads();
        *(float4*)&As[lrow][lcol] = *(const float4*)&Ab[(size_t)(kc + lrow) * N_ + n0 + lcol];
        *(float4*)&Bs[lrow][lcol] = *(const float4*)&q_w[(kc + lrow) * C_ + c0 + lcol];
        __syncthreads();
#pragma unroll
        for (int kk = 0; kk < 16; ++kk) {
            float4 a4 = *(const float4*)&As[kk][tn * 4];
            float4 b4 = *(const float4*)&Bs[kk][tc * 4];
            float av[4] = {a4.x, a4.y, a4.z, a4.w};
            float bv[4] = {b4.x, b4.y, b4.z, b4.w};
#pragma unroll
            for (int i = 0; i < 4; ++i)
#pragma unroll
                for (int j = 0; j < 4; ++j)
                    acc[i][j] += av[i] * bv[j];
        }
    }
    __syncthreads();
#pragma unroll
    for (int i = 0; i < 4; ++i)
#pragma unroll
        for (int j = 0; j < 4; ++j)
            qs[tn * 4 + i][tc * 4 + j] = acc[i][j] + q_b[c0 + tc * 4 + j];
    __syncthreads();

    // RoPE + store
    for (int idx = tid; idx < 64 * 64; idx += 256) {
        int nn = idx >> 6, cc = idx & 63;
        int n = n0 + nn;
        int co = c0 + cc;
        int t = cc & 31;           // head-dim index (c0 % 64 == 0)
        int nh = co >> 5;
        float val = qs[nn][cc];
        float par = (t < 16) ? -qs[nn][cc + 16] : qs[nn][cc - 16];
        int d = n >> 10, hh = (n >> 5) & 31, w = n & 31;
        float pos, ex;
        if (t < 10)      { int j = t % 5;        pos = (float)d;  ex = (float)(2 * j) * 0.1f; }
        else if (t < 20) { int j = (t - 10) % 5; pos = (float)hh; ex = (float)(2 * j) * 0.1f; }
        else             { int j = (t - 20) % 6; pos = (float)w;  ex = (float)(2 * j) * (1.0f / 12.0f); }
        float f = pos * expf(-ex * 9.210340371976184f);  // pos * 10000^-ex
        float qr = val * cosf(f) + par * sinf(f);
        q_rot[((size_t)(b * NHD + nh) * N_ + n) * HD + t] = qr;
    }
}

// ---------------------------------------------------------------------------
// Kernel 3: attention. Per (b,nh): q_rot[N][32] x k_rot[256][32] -> softmax
// (no max-sub: scores are O(1)) -> @ v[256][32]. K/V staged in LDS (fp32).
// Each thread owns 2 rows (lane-consecutive for coalesced stores).
// Output written transposed: out_t[B][C][N], c = nh*32+hd.
// ---------------------------------------------------------------------------
__global__ __launch_bounds__(256) void attn_kernel(
    const float* __restrict__ q_rot,
    const float* __restrict__ k_rot,
    const float* __restrict__ v_in,
    float* __restrict__ out_t)
{
    __shared__ float ks[S_][HD];   // 32 KB
    __shared__ float vs[S_][HD];   // 32 KB
    const int tid = threadIdx.x;
    const int bh = blockIdx.y;     // b*8+nh
    const float* kb = k_rot + (size_t)bh * S_ * HD;
    const float* vb = v_in + (size_t)bh * S_ * HD;
    for (int i = tid; i < S_ * HD / 4; i += 256) {
        ((float4*)ks)[i] = ((const float4*)kb)[i];
        ((float4*)vs)[i] = ((const float4*)vb)[i];
    }
    __syncthreads();

    const int r0 = blockIdx.x * 512 + tid;
    const int r1 = r0 + 256;
    const float4* q0p = (const float4*)(q_rot + ((size_t)bh * N_ + r0) * HD);
    const float4* q1p = (const float4*)(q_rot + ((size_t)bh * N_ + r1) * HD);
    float4 q0[8], q1[8], o0[8], o1[8];
#pragma unroll
    for (int i = 0; i < 8; ++i) {
        q0[i] = q0p[i]; q1[i] = q1p[i];
        o0[i] = make_float4(0.f, 0.f, 0.f, 0.f);
        o1[i] = make_float4(0.f, 0.f, 0.f, 0.f);
    }
    float l0 = 0.f, l1 = 0.f;
    const float scale = 0.17677669529663687f;  // 32^-0.5

    for (int s = 0; s < S_; ++s) {
        const float4* krow = (const float4*)&ks[s][0];
        float sc0 = 0.f, sc1 = 0.f;
#pragma unroll
        for (int i = 0; i < 8; ++i) {
            float4 k4 = krow[i];
            sc0 += q0[i].x * k4.x + q0[i].y * k4.y + q0[i].z * k4.z + q0[i].w * k4.w;
            sc1 += q1[i].x * k4.x + q1[i].y * k4.y + q1[i].z * k4.z + q1[i].w * k4.w;
        }
        float p0 = __expf(sc0 * scale);
        float p1 = __expf(sc1 * scale);
        l0 += p0; l1 += p1;
        const float4* vrow = (const float4*)&vs[s][0];
#pragma unroll
        for (int i = 0; i < 8; ++i) {
            float4 v4 = vrow[i];
            o0[i].x += p0 * v4.x; o0[i].y += p0 * v4.y; o0[i].z += p0 * v4.z; o0[i].w += p0 * v4.w;
            o1[i].x += p1 * v4.x; o1[i].y += p1 * v4.y; o1[i].z += p1 * v4.z; o1[i].w += p1 * v4.w;
        }
    }
    float i0 = 1.f / l0, i1 = 1.f / l1;
    int b = bh >> 3, nh = bh & 7;
    float* ob = out_t + (size_t)(b * C_ + nh * HD) * N_;
#pragma unroll
    for (int i = 0; i < 8; ++i) {
        ob[(size_t)(i * 4 + 0) * N_ + r0] = o0[i].x * i0;
        ob[(size_t)(i * 4 + 1) * N_ + r0] = o0[i].y * i0;
        ob[(size_t)(i * 4 + 2) * N_ + r0] = o0[i].z * i0;
        ob[(size_t)(i * 4 + 3) * N_ + r0] = o0[i].w * i0;
        ob[(size_t)(i * 4 + 0) * N_ + r1] = o1[i].x * i1;
        ob[(size_t)(i * 4 + 1) * N_ + r1] = o1[i].y * i1;
        ob[(size_t)(i * 4 + 2) * N_ + r1] = o1[i].z * i1;
        ob[(size_t)(i * 4 + 3) * N_ + r1] = o1[i].w * i1;
    }
}

// ---------------------------------------------------------------------------
// Kernel 4: output projection. A = out_t[b] [C][N] (K-major), B = o_w [C][C].
// out[b][co][n] = sum_c A[c][n]*o_w[c][co] + o_b[co]. Same tiling as kernel 2.
// ---------------------------------------------------------------------------
__global__ __launch_bounds__(256) void oproj(
    const float* __restrict__ A,
    const float* __restrict__ o_w, const float* __restrict__ o_b,
    float* __restrict__ out)
{
    __shared__ float As[16][64];
    __shared__ float Bs[16][64];
    const int tid = threadIdx.x;
    const int tn = tid & 15, tc = tid >> 4;
    const int n0 = blockIdx.x * 64, c0 = blockIdx.y * 64, b = blockIdx.z;
    const float* Ab = A + (size_t)b * C_ * N_;
    const int lrow = tid >> 4, lcol = (tid & 15) * 4;

    float acc[4][4] = {};
    for (int kc = 0; kc < C_; kc += 16) {
        __syncthreads();
        *(float4*)&As[lrow][lcol] = *(const float4*)&Ab[(size_t)(kc + lrow) * N_ + n0 + lcol];
        *(float4*)&Bs[lrow][lcol] = *(const float4*)&o_w[(kc + lrow) * C_ + c0 + lcol];
        __syncthreads();
#pragma unroll
        for (int kk = 0; kk < 16; ++kk) {
            float4 a4 = *(const float4*)&As[kk][tn * 4];
            float4 b4 = *(const float4*)&Bs[kk][tc * 4];
            float av[4] = {a4.x, a4.y, a4.z, a4.w};
            float bv[4] = {b4.x, b4.y, b4.z, b4.w};
#pragma unroll
            for (int i = 0; i < 4; ++i)
#pragma unroll
                for (int j = 0; j < 4; ++j)
                    acc[i][j] += av[i] * bv[j];
        }
    }
#pragma unroll
    for (int j = 0; j < 4; ++j) {
        int co = c0 + tc * 4 + j;
        float bias = o_b[co];
        float4 vsto = make_float4(acc[0][j] + bias, acc[1][j] + bias,
                                  acc[2][j] + bias, acc[3][j] + bias);
        *(float4*)&out[(size_t)(b * C_ + co) * N_ + n0 + tn * 4] = vsto;
    }
}

// ---------------------------------------------------------------------------
extern "C" void kernel_launch(void* const* d_in, const int* in_sizes, int n_in,
                              void* d_out, int out_size, void* d_ws, size_t ws_size,
                              hipStream_t stream) {
    (void)in_sizes; (void)n_in; (void)out_size; (void)ws_size;
    const float* fv   = (const float*)d_in[0];
    const float* text = (const float*)d_in[1];
    const float* q_w  = (const float*)d_in[2];
    const float* q_b  = (const float*)d_in[3];
    const float* k_w  = (const float*)d_in[4];
    const float* k_b  = (const float*)d_in[5];
    const float* v_w  = (const float*)d_in[6];
    const float* v_b  = (const float*)d_in[7];
    const float* o_w  = (const float*)d_in[8];
    const float* o_b  = (const float*)d_in[9];
    const float* m1_w = (const float*)d_in[10];
    const float* m1_b = (const float*)d_in[11];
    const float* m2_w = (const float*)d_in[12];
    const float* m2_b = (const float*)d_in[13];
    float* out = (float*)d_out;

    float* wsf    = (float*)d_ws;
    float* k_rot  = wsf;                               // 131072 f
    float* v_t    = wsf + 131072;                      // 131072 f
    float* q_rot  = wsf + 262144;                      // 16777216 f
    float* attn_t = wsf + 262144 + 16777216;           // 16777216 f  (total ~135 MB)

    hipLaunchKernelGGL(text_stage, dim3(128), dim3(256), 0, stream,
                       text, k_w, k_b, v_w, v_b, m1_w, m1_b, m2_w, m2_b, k_rot, v_t);
    hipLaunchKernelGGL(qproj_rope, dim3(512, 4, 2), dim3(256), 0, stream,
                       fv, q_w, q_b, q_rot);
    hipLaunchKernelGGL(attn_kernel, dim3(64, 16), dim3(256), 0, stream,
                       q_rot, k_rot, v_t, attn_t);
    hipLaunchKernelGGL(oproj, dim3(512, 4, 2), dim3(256), 0, stream,
                       attn_t, o_w, o_b, out);
}

// Round 3
// 403.598 us; speedup vs baseline: 1.8277x; 1.8277x over previous
//
#include <hip/hip_runtime.h>
#include <hip/hip_bf16.h>

#define NHD 8
#define HD  32
#define C_  256
#define TD_ 512
#define S_  256
#define N_  32768   // D*H*W
#define B_  2

typedef short bf16x8 __attribute__((ext_vector_type(8)));
typedef float f32x4  __attribute__((ext_vector_type(4)));

#define MFMA16(a,b,c) __builtin_amdgcn_mfma_f32_16x16x32_bf16(a,b,c,0,0,0)

__device__ __forceinline__ short f2bf(float f){
    __hip_bfloat16 h = __float2bfloat16(f);
    return *reinterpret_cast<short*>(&h);
}

// ---------------------------------------------------------------------------
// prep: transpose q_w, o_w (fp32 [c][co]) -> bf16 W^T [co][c]
// ---------------------------------------------------------------------------
__global__ __launch_bounds__(256) void prep_w(
    const float* __restrict__ qw, const float* __restrict__ ow,
    short* __restrict__ wtq, short* __restrict__ wto)
{
    int gid = blockIdx.x * 256 + threadIdx.x;   // grid 512 -> 131072
    int m = gid >> 16;
    int e = gid & 65535;
    int c = e >> 8, co = e & 255;
    const float* src = m ? ow : qw;
    short* dst = m ? wto : wtq;
    dst[co * 256 + c] = f2bf(src[c * 256 + co]);
}

// ---------------------------------------------------------------------------
// text stage: K/V proj + GELU MLP + learned-phase RoPE on K. fp32 math,
// bf16 outputs: k_rot [bh][s][hd], v_t [bh][hd][s].
// ---------------------------------------------------------------------------
__global__ __launch_bounds__(256) void text_stage(
    const float* __restrict__ text,
    const float* __restrict__ k_w, const float* __restrict__ k_b,
    const float* __restrict__ v_w, const float* __restrict__ v_b,
    const float* __restrict__ m1_w, const float* __restrict__ m1_b,
    const float* __restrict__ m2_w, const float* __restrict__ m2_b,
    short* __restrict__ k_rot, short* __restrict__ v_t)
{
    __shared__ float t_s[4][TD_];
    __shared__ float h_s[4][C_];
    __shared__ float k_s[4][C_];
    const int tid = threadIdx.x;
    const int token0 = blockIdx.x * 4;

    for (int i = tid; i < 4 * TD_; i += 256)
        t_s[i >> 9][i & (TD_ - 1)] = text[(size_t)token0 * TD_ + i];
    __syncthreads();

    float kv[4], vv[4], hv[4];
#pragma unroll
    for (int tk = 0; tk < 4; ++tk) { kv[tk] = k_b[tid]; vv[tk] = v_b[tid]; hv[tk] = m1_b[tid]; }

    for (int j = 0; j < TD_; ++j) {
        float wk = k_w[j * C_ + tid];
        float wvv = v_w[j * C_ + tid];
        float wm = m1_w[j * C_ + tid];
#pragma unroll
        for (int tk = 0; tk < 4; ++tk) {
            float tj = t_s[tk][j];
            kv[tk] += tj * wk; vv[tk] += tj * wvv; hv[tk] += tj * wm;
        }
    }
#pragma unroll
    for (int tk = 0; tk < 4; ++tk) {
        float h = hv[tk];
        h = 0.5f * h * (1.0f + erff(h * 0.70710678118654752f));
        h_s[tk][tid] = h;
        k_s[tk][tid] = kv[tk];
    }
    __syncthreads();

    float ph[4];
#pragma unroll
    for (int tk = 0; tk < 4; ++tk) ph[tk] = m2_b[tid];
    for (int j = 0; j < C_; ++j) {
        float wm = m2_w[j * C_ + tid];
#pragma unroll
        for (int tk = 0; tk < 4; ++tk) ph[tk] += h_s[tk][j] * wm;
    }

    const int t = tid & (HD - 1);
    const int nh = tid >> 5;
#pragma unroll
    for (int tk = 0; tk < 4; ++tk) {
        int token = token0 + tk;
        int b = token >> 8, s = token & (S_ - 1);
        float partner = (t < 16) ? -k_s[tk][tid + 16] : k_s[tk][tid - 16];
        float kr = kv[tk] * cosf(ph[tk]) + partner * sinf(ph[tk]);
        k_rot[((size_t)(b * NHD + nh) * S_ + s) * HD + t] = f2bf(kr);
        v_t[((size_t)(b * NHD + nh) * HD + t) * S_ + s]   = f2bf(vv[tk]);
    }
}

// 3D rope freq for head-dim index t (0..31) at flat position n (verified R1)
__device__ __forceinline__ float freq3d(int t, int n){
    int d = n >> 10, h = (n >> 5) & 31, w = n & 31;
    float pos, ex;
    if (t < 10)      { pos = (float)d; ex = (float)(2 * (t % 5)) * 0.1f; }
    else if (t < 20) { pos = (float)h; ex = (float)(2 * ((t - 10) % 5)) * 0.1f; }
    else             { pos = (float)w; ex = (float)(2 * ((t - 20) % 6)) * (1.0f / 12.0f); }
    return pos * expf(-ex * 9.210340371976184f);
}

// ---------------------------------------------------------------------------
// qproj + fused RoPE (MFMA). Block: 64 n-rows x all 256 co. 4 waves x M=16.
// A = fv^T (LDS transpose-staged, pitch 36), B = wt_q global b128 frags.
// Output q_rot bf16 [bh][n][32].
// ---------------------------------------------------------------------------
__global__ __launch_bounds__(256) void qproj_rope(
    const float* __restrict__ fv, const short* __restrict__ wt_q,
    const float* __restrict__ q_b, short* __restrict__ q_rot)
{
    __shared__ short At[64 * 36];
    const int tid = threadIdx.x;
    const int l15 = tid & 15, qd = (tid >> 4) & 3, wv = tid >> 6;
    const int n0 = blockIdx.x * 64;
    const int b = blockIdx.y;
    const f32x4 z4 = {0.f, 0.f, 0.f, 0.f};
    f32x4 acc[16];
#pragma unroll
    for (int i = 0; i < 16; ++i) acc[i] = z4;
    const int cr = tid >> 3;        // local c row 0..31
    const int nb = (tid & 7) * 8;   // local n block

    for (int c0 = 0; c0 < 256; c0 += 32) {
        __syncthreads();
        const float* src = fv + ((size_t)(b * C_ + c0 + cr)) * N_ + n0 + nb;
        float4 f0 = *(const float4*)src;
        float4 f1 = *(const float4*)(src + 4);
        At[(nb + 0) * 36 + cr] = f2bf(f0.x); At[(nb + 1) * 36 + cr] = f2bf(f0.y);
        At[(nb + 2) * 36 + cr] = f2bf(f0.z); At[(nb + 3) * 36 + cr] = f2bf(f0.w);
        At[(nb + 4) * 36 + cr] = f2bf(f1.x); At[(nb + 5) * 36 + cr] = f2bf(f1.y);
        At[(nb + 6) * 36 + cr] = f2bf(f1.z); At[(nb + 7) * 36 + cr] = f2bf(f1.w);
        __syncthreads();
        bf16x8 af = *(const bf16x8*)&At[(wv * 16 + l15) * 36 + qd * 8];
#pragma unroll
        for (int nt = 0; nt < 16; ++nt) {
            bf16x8 bf = *(const bf16x8*)&wt_q[(size_t)(l15 + 16 * nt) * 256 + c0 + qd * 8];
            acc[nt] = MFMA16(af, bf, acc[nt]);
        }
    }
    // RoPE epilogue, fully in-register: pair (t,t+16) lives in regs (2h, 2h+1)
#pragma unroll
    for (int r = 0; r < 4; ++r) {
        int n = n0 + wv * 16 + qd * 4 + r;
        float f1 = freq3d(l15, n), f2 = freq3d(l15 + 16, n);
        float c1 = cosf(f1), s1 = sinf(f1), c2 = cosf(f2), s2 = sinf(f2);
#pragma unroll
        for (int hh = 0; hh < 8; ++hh) {
            float x1 = acc[2 * hh][r]     + q_b[32 * hh + l15];
            float x2 = acc[2 * hh + 1][r] + q_b[32 * hh + 16 + l15];
            float o1 = x1 * c1 - x2 * s1;
            float o2 = x2 * c2 + x1 * s2;
            size_t base = ((size_t)(b * NHD + hh) * N_ + n) * HD;
            q_rot[base + l15]      = f2bf(o1);
            q_rot[base + 16 + l15] = f2bf(o2);
        }
    }
}

// ---------------------------------------------------------------------------
// attention (MFMA). Block: one (b,h) x 64 q-rows. 4 waves x M=16.
// LDS: Ks [256][32] xor-swizzled (16KB, aliased by P), P 4x[16][260] (33280B),
// Vt [32][256] xor-swizzled (16KB). Total 49664 B.
// ---------------------------------------------------------------------------
__global__ __launch_bounds__(256) void attn_mfma(
    const short* __restrict__ q_rot, const short* __restrict__ k_rot,
    const short* __restrict__ v_t, short* __restrict__ attn_nc)
{
    __shared__ short smem[24832];
    short* Ks = smem;            // phase (a) only
    short* P  = smem;            // phase (b/c), aliases Ks (barrier-guarded)
    short* Vt = smem + 16640;    // 33280 B offset
    const int tid = threadIdx.x;
    const int l15 = tid & 15, qd = (tid >> 4) & 3, wv = tid >> 6;
    const int n0 = blockIdx.x * 64;
    const int bh = blockIdx.y;
    const f32x4 z4 = {0.f, 0.f, 0.f, 0.f};

    for (int i = tid; i < 1024; i += 256) {         // K: 256 rows x 4 parts
        int s = i >> 2, part = i & 3;
        int pp = part ^ ((s >> 1) & 3);
        *(bf16x8*)&Ks[s * 32 + pp * 8] =
            *(const bf16x8*)&k_rot[(size_t)bh * 8192 + s * 32 + part * 8];
    }
    for (int i = tid; i < 1024; i += 256) {         // Vt: 32 rows x 32 parts
        int d = i >> 5, part = i & 31;
        int pp = part ^ (d & 7);
        *(bf16x8*)&Vt[d * 256 + pp * 8] =
            *(const bf16x8*)&v_t[(size_t)bh * 8192 + d * 256 + part * 8];
    }
    bf16x8 aq = *(const bf16x8*)&q_rot[((size_t)bh * N_ + n0 + wv * 16 + l15) * HD + qd * 8];
    __syncthreads();

    f32x4 sc[16];
#pragma unroll
    for (int st = 0; st < 16; ++st) {
        int srow = st * 16 + l15;
        int pp = qd ^ ((srow >> 1) & 3);
        bf16x8 bk = *(const bf16x8*)&Ks[srow * 32 + pp * 8];
        sc[st] = MFMA16(aq, bk, z4);
    }
    const float scale = 0.17677669529663687f;
#pragma unroll
    for (int st = 0; st < 16; ++st)
#pragma unroll
        for (int r = 0; r < 4; ++r)
            sc[st][r] = __expf(sc[st][r] * scale);

    float il[4];
#pragma unroll
    for (int r = 0; r < 4; ++r) {
        float t = 0.f;
#pragma unroll
        for (int st = 0; st < 16; ++st) t += sc[st][r];
        t += __shfl_xor(t, 1); t += __shfl_xor(t, 2);
        t += __shfl_xor(t, 4); t += __shfl_xor(t, 8);
        il[r] = 1.f / t;
    }
    __syncthreads();   // all waves done reading Ks
#pragma unroll
    for (int st = 0; st < 16; ++st)
#pragma unroll
        for (int r = 0; r < 4; ++r)
            P[wv * 4160 + (qd * 4 + r) * 260 + st * 16 + l15] = f2bf(sc[st][r]);
    __syncthreads();

    f32x4 o0 = z4, o1 = z4;
#pragma unroll
    for (int kt = 0; kt < 8; ++kt) {
        bf16x8 pa = *(const bf16x8*)&P[wv * 4160 + l15 * 260 + kt * 32 + qd * 8];
        int blk = kt * 4 + qd;
        bf16x8 v0 = *(const bf16x8*)&Vt[l15 * 256 + (blk ^ (l15 & 7)) * 8];
        bf16x8 v1 = *(const bf16x8*)&Vt[(l15 + 16) * 256 + (blk ^ ((l15 + 16) & 7)) * 8];
        o0 = MFMA16(pa, v0, o0);
        o1 = MFMA16(pa, v1, o1);
    }
    int b = bh >> 3, h = bh & 7;
#pragma unroll
    for (int r = 0; r < 4; ++r) {
        int n = n0 + wv * 16 + qd * 4 + r;
        size_t base = ((size_t)b * N_ + n) * C_ + h * HD;
        attn_nc[base + l15]      = f2bf(o0[r] * il[r]);
        attn_nc[base + 16 + l15] = f2bf(o1[r] * il[r]);
    }
}

// ---------------------------------------------------------------------------
// oproj (MFMA, no LDS). Block: all 256 co x 64 n. Wave: 64 co x 64 n.
// A = wt_o global frags, B = attn_nc global frags. C-layout rows=co ->
// coalesced fp32 stores in output layout [B][C][N].
// ---------------------------------------------------------------------------
__global__ __launch_bounds__(256) void oproj_mfma(
    const short* __restrict__ attn_nc, const short* __restrict__ wt_o,
    const float* __restrict__ o_b, float* __restrict__ out)
{
    const int tid = threadIdx.x;
    const int l15 = tid & 15, qd = (tid >> 4) & 3, wv = tid >> 6;
    const int n0 = blockIdx.x * 64;
    const int b = blockIdx.y;
    const int co0 = wv * 64;
    const f32x4 z4 = {0.f, 0.f, 0.f, 0.f};
    f32x4 acc[4][4];
#pragma unroll
    for (int i = 0; i < 4; ++i)
#pragma unroll
        for (int j = 0; j < 4; ++j) acc[i][j] = z4;

    for (int c0 = 0; c0 < 256; c0 += 32) {
        bf16x8 bfr[4];
#pragma unroll
        for (int nt = 0; nt < 4; ++nt)
            bfr[nt] = *(const bf16x8*)&attn_nc[((size_t)b * N_ + n0 + nt * 16 + l15) * C_ + c0 + qd * 8];
#pragma unroll
        for (int mt = 0; mt < 4; ++mt) {
            bf16x8 afr = *(const bf16x8*)&wt_o[(size_t)(co0 + mt * 16 + l15) * 256 + c0 + qd * 8];
#pragma unroll
            for (int nt = 0; nt < 4; ++nt)
                acc[mt][nt] = MFMA16(afr, bfr[nt], acc[mt][nt]);
        }
    }
#pragma unroll
    for (int mt = 0; mt < 4; ++mt)
#pragma unroll
        for (int r = 0; r < 4; ++r) {
            int co = co0 + mt * 16 + qd * 4 + r;
            float bias = o_b[co];
#pragma unroll
            for (int nt = 0; nt < 4; ++nt)
                out[((size_t)(b * C_ + co)) * N_ + n0 + nt * 16 + l15] = acc[mt][nt][r] + bias;
        }
}

// ---------------------------------------------------------------------------
extern "C" void kernel_launch(void* const* d_in, const int* in_sizes, int n_in,
                              void* d_out, int out_size, void* d_ws, size_t ws_size,
                              hipStream_t stream) {
    (void)in_sizes; (void)n_in; (void)out_size; (void)ws_size;
    const float* fv   = (const float*)d_in[0];
    const float* text = (const float*)d_in[1];
    const float* q_w  = (const float*)d_in[2];
    const float* q_b  = (const float*)d_in[3];
    const float* k_w  = (const float*)d_in[4];
    const float* k_b  = (const float*)d_in[5];
    const float* v_w  = (const float*)d_in[6];
    const float* v_b  = (const float*)d_in[7];
    const float* o_w  = (const float*)d_in[8];
    const float* o_b  = (const float*)d_in[9];
    const float* m1_w = (const float*)d_in[10];
    const float* m1_b = (const float*)d_in[11];
    const float* m2_w = (const float*)d_in[12];
    const float* m2_b = (const float*)d_in[13];
    float* out = (float*)d_out;

    short* wsS   = (short*)d_ws;
    short* k_rot = wsS;                      // 131072
    short* v_t   = wsS + 131072;             // 131072
    short* wt_q  = wsS + 262144;             // 65536
    short* wt_o  = wsS + 327680;             // 65536
    short* q_rot = wsS + 393216;             // 16777216
    short* attn  = wsS + 17170432;           // 16777216

    hipLaunchKernelGGL(prep_w, dim3(512), dim3(256), 0, stream, q_w, o_w, wt_q, wt_o);
    hipLaunchKernelGGL(text_stage, dim3(128), dim3(256), 0, stream,
                       text, k_w, k_b, v_w, v_b, m1_w, m1_b, m2_w, m2_b, k_rot, v_t);
    hipLaunchKernelGGL(qproj_rope, dim3(512, 2), dim3(256), 0, stream,
                       fv, wt_q, q_b, q_rot);
    hipLaunchKernelGGL(attn_mfma, dim3(512, 16), dim3(256), 0, stream,
                       q_rot, k_rot, v_t, attn);
    hipLaunchKernelGGL(oproj_mfma, dim3(512, 2), dim3(256), 0, stream,
                       attn, wt_o, o_b, out);
}

// Round 4
// 395.581 us; speedup vs baseline: 1.8647x; 1.0203x over previous
//
#include <hip/hip_runtime.h>
#include <hip/hip_bf16.h>

#define NHD 8
#define HD  32
#define C_  256
#define TD_ 512
#define S_  256
#define N_  32768   // D*H*W
#define B_  2

typedef short bf16x8 __attribute__((ext_vector_type(8)));
typedef float f32x4  __attribute__((ext_vector_type(4)));

#define MFMA16(a,b,c) __builtin_amdgcn_mfma_f32_16x16x32_bf16(a,b,c,0,0,0)

__device__ __forceinline__ short f2bf(float f){
    __hip_bfloat16 h = __float2bfloat16(f);
    return *reinterpret_cast<short*>(&h);
}

// ---------------------------------------------------------------------------
// prep: transpose q_w, o_w (fp32 [c][co]) -> bf16 W^T [co][c]
// ---------------------------------------------------------------------------
__global__ __launch_bounds__(256) void prep_w(
    const float* __restrict__ qw, const float* __restrict__ ow,
    short* __restrict__ wtq, short* __restrict__ wto)
{
    int gid = blockIdx.x * 256 + threadIdx.x;   // grid 512 -> 131072
    int m = gid >> 16;
    int e = gid & 65535;
    int c = e >> 8, co = e & 255;
    const float* src = m ? ow : qw;
    short* dst = m ? wto : wtq;
    dst[co * 256 + c] = f2bf(src[c * 256 + co]);
}

// ---------------------------------------------------------------------------
// text stage: K/V proj + GELU MLP + learned-phase RoPE on K. fp32 math,
// bf16 outputs: k_rot [bh][s][hd], v_t [bh][hd][s].  (verified R3)
// ---------------------------------------------------------------------------
__global__ __launch_bounds__(256) void text_stage(
    const float* __restrict__ text,
    const float* __restrict__ k_w, const float* __restrict__ k_b,
    const float* __restrict__ v_w, const float* __restrict__ v_b,
    const float* __restrict__ m1_w, const float* __restrict__ m1_b,
    const float* __restrict__ m2_w, const float* __restrict__ m2_b,
    short* __restrict__ k_rot, short* __restrict__ v_t)
{
    __shared__ float t_s[4][TD_];
    __shared__ float h_s[4][C_];
    __shared__ float k_s[4][C_];
    const int tid = threadIdx.x;
    const int token0 = blockIdx.x * 4;

    for (int i = tid; i < 4 * TD_; i += 256)
        t_s[i >> 9][i & (TD_ - 1)] = text[(size_t)token0 * TD_ + i];
    __syncthreads();

    float kv[4], vv[4], hv[4];
#pragma unroll
    for (int tk = 0; tk < 4; ++tk) { kv[tk] = k_b[tid]; vv[tk] = v_b[tid]; hv[tk] = m1_b[tid]; }

    for (int j = 0; j < TD_; ++j) {
        float wk = k_w[j * C_ + tid];
        float wvv = v_w[j * C_ + tid];
        float wm = m1_w[j * C_ + tid];
#pragma unroll
        for (int tk = 0; tk < 4; ++tk) {
            float tj = t_s[tk][j];
            kv[tk] += tj * wk; vv[tk] += tj * wvv; hv[tk] += tj * wm;
        }
    }
#pragma unroll
    for (int tk = 0; tk < 4; ++tk) {
        float h = hv[tk];
        h = 0.5f * h * (1.0f + erff(h * 0.70710678118654752f));
        h_s[tk][tid] = h;
        k_s[tk][tid] = kv[tk];
    }
    __syncthreads();

    float ph[4];
#pragma unroll
    for (int tk = 0; tk < 4; ++tk) ph[tk] = m2_b[tid];
    for (int j = 0; j < C_; ++j) {
        float wm = m2_w[j * C_ + tid];
#pragma unroll
        for (int tk = 0; tk < 4; ++tk) ph[tk] += h_s[tk][j] * wm;
    }

    const int t = tid & (HD - 1);
    const int nh = tid >> 5;
#pragma unroll
    for (int tk = 0; tk < 4; ++tk) {
        int token = token0 + tk;
        int b = token >> 8, s = token & (S_ - 1);
        float partner = (t < 16) ? -k_s[tk][tid + 16] : k_s[tk][tid - 16];
        float kr = kv[tk] * cosf(ph[tk]) + partner * sinf(ph[tk]);
        k_rot[((size_t)(b * NHD + nh) * S_ + s) * HD + t] = f2bf(kr);
        v_t[((size_t)(b * NHD + nh) * HD + t) * S_ + s]   = f2bf(vv[tk]);
    }
}

// 3D rope freq for head-dim index t (0..31) at flat position n (verified R3)
__device__ __forceinline__ float freq3d(int t, int n){
    int d = n >> 10, h = (n >> 5) & 31, w = n & 31;
    float pos, ex;
    if (t < 10)      { pos = (float)d; ex = (float)(2 * (t % 5)) * 0.1f; }
    else if (t < 20) { pos = (float)h; ex = (float)(2 * ((t - 10) % 5)) * 0.1f; }
    else             { pos = (float)w; ex = (float)(2 * ((t - 20) % 6)) * (1.0f / 12.0f); }
    return pos * expf(-ex * 9.210340371976184f);
}

// ---------------------------------------------------------------------------
// FUSED visual pipeline: qproj + RoPE + attention + oproj, one block = 64 n
// rows of one batch. 4 waves, each owns 16 rows. ZERO __syncthreads: all LDS
// regions (Qs, P, Ot) are wave-private layout-transform buffers.
//   qproj:  A-frags = 8 strided global dword loads of fv (no LDS transpose),
//           B-frags = wt_q [co][c] b128 (L2-hot).
//   scores: A = Qs LDS b128 (pitch 264), B = k_rot [s][hd] global b128.
//   PV:     A = P LDS round-trip (pitch 264), B = v_t [hd][s] global b128.
//   oproj:  accumulated over heads: out += (P_h V_h) @ o_w[h*32:(h+1)*32,:]
//           A = wt_o [co][c] b128, B = o-tile LDS round-trip (pitch 40).
// ---------------------------------------------------------------------------
__global__ __launch_bounds__(256, 2) void fused_visual(
    const float* __restrict__ fv, const short* __restrict__ wt_q,
    const float* __restrict__ q_b, const short* __restrict__ k_rot,
    const short* __restrict__ v_t, const short* __restrict__ wt_o,
    const float* __restrict__ o_b, float* __restrict__ out)
{
    __shared__ short Qs[64 * 264];      // [n_local][co], pitch 264
    __shared__ short Pb[4 * 16 * 264];  // per-wave [16][264]
    __shared__ short Ot[4 * 16 * 40];   // per-wave [16][40]
    const int tid = threadIdx.x;
    const int l15 = tid & 15, qd = (tid >> 4) & 3, wv = tid >> 6;
    const int n0 = blockIdx.x * 64;
    const int b = blockIdx.y;
    const f32x4 z4 = {0.f, 0.f, 0.f, 0.f};
    const float scale = 0.17677669529663687f;  // 32^-0.5, folded into Q

    // ---------------- qproj ----------------
    {
        f32x4 acc[16];
#pragma unroll
        for (int i = 0; i < 16; ++i) acc[i] = z4;
        const int nrow = n0 + wv * 16 + l15;
        for (int c0 = 0; c0 < 256; c0 += 32) {
            bf16x8 af;
#pragma unroll
            for (int j = 0; j < 8; ++j)
                af[j] = f2bf(fv[(size_t)(b * C_ + c0 + qd * 8 + j) * N_ + nrow]);
#pragma unroll
            for (int nt = 0; nt < 16; ++nt) {
                bf16x8 bq = *(const bf16x8*)&wt_q[(size_t)(nt * 16 + l15) * 256 + c0 + qd * 8];
                acc[nt] = MFMA16(af, bq, acc[nt]);
            }
        }
        // RoPE epilogue -> Qs (scale folded in)
#pragma unroll
        for (int r = 0; r < 4; ++r) {
            int n = n0 + wv * 16 + qd * 4 + r;
            float f1 = freq3d(l15, n), f2 = freq3d(l15 + 16, n);
            float c1 = cosf(f1), s1 = sinf(f1), c2 = cosf(f2), s2 = sinf(f2);
            int row = (wv * 16 + qd * 4 + r) * 264;
#pragma unroll
            for (int hh = 0; hh < 8; ++hh) {
                float x1 = acc[2 * hh][r]     + q_b[hh * 32 + l15];
                float x2 = acc[2 * hh + 1][r] + q_b[hh * 32 + 16 + l15];
                Qs[row + hh * 32 + l15]      = f2bf((x1 * c1 - x2 * s1) * scale);
                Qs[row + hh * 32 + 16 + l15] = f2bf((x2 * c2 + x1 * s2) * scale);
            }
        }
    }

    // ---------------- attention + accumulated oproj ----------------
    f32x4 acc_co[16];
#pragma unroll
    for (int i = 0; i < 16; ++i) acc_co[i] = z4;
    short* Pw = Pb + wv * 16 * 264;
    short* Ow = Ot + wv * 16 * 40;

    for (int h = 0; h < 8; ++h) {
        const int bh = b * NHD + h;
        const short* kbase = k_rot + (size_t)bh * (S_ * HD);
        const short* vbase = v_t + (size_t)bh * (S_ * HD);

        bf16x8 aq = *(const bf16x8*)&Qs[(wv * 16 + l15) * 264 + h * 32 + qd * 8];
        f32x4 sc[16];
#pragma unroll
        for (int st = 0; st < 16; ++st) {
            bf16x8 bk = *(const bf16x8*)&kbase[(st * 16 + l15) * 32 + qd * 8];
            sc[st] = MFMA16(aq, bk, z4);
        }
#pragma unroll
        for (int st = 0; st < 16; ++st)
#pragma unroll
            for (int r = 0; r < 4; ++r)
                sc[st][r] = __expf(sc[st][r]);

        float il[4];
#pragma unroll
        for (int r = 0; r < 4; ++r) {
            float t = 0.f;
#pragma unroll
            for (int st = 0; st < 16; ++st) t += sc[st][r];
            t += __shfl_xor(t, 1); t += __shfl_xor(t, 2);
            t += __shfl_xor(t, 4); t += __shfl_xor(t, 8);
            il[r] = 1.f / t;
        }
#pragma unroll
        for (int st = 0; st < 16; ++st)
#pragma unroll
            for (int r = 0; r < 4; ++r)
                Pw[(qd * 4 + r) * 264 + st * 16 + l15] = f2bf(sc[st][r]);

        f32x4 o0 = z4, o1 = z4;
#pragma unroll
        for (int kt = 0; kt < 8; ++kt) {
            bf16x8 pa = *(const bf16x8*)&Pw[l15 * 264 + kt * 32 + qd * 8];
            bf16x8 v0 = *(const bf16x8*)&vbase[(size_t)l15 * 256 + kt * 32 + qd * 8];
            bf16x8 v1 = *(const bf16x8*)&vbase[(size_t)(l15 + 16) * 256 + kt * 32 + qd * 8];
            o0 = MFMA16(pa, v0, o0);
            o1 = MFMA16(pa, v1, o1);
        }
#pragma unroll
        for (int r = 0; r < 4; ++r) {
            Ow[(qd * 4 + r) * 40 + l15]      = f2bf(o0[r] * il[r]);
            Ow[(qd * 4 + r) * 40 + 16 + l15] = f2bf(o1[r] * il[r]);
        }
        bf16x8 bo = *(const bf16x8*)&Ow[l15 * 40 + qd * 8];
#pragma unroll
        for (int mt = 0; mt < 16; ++mt) {
            bf16x8 ao = *(const bf16x8*)&wt_o[(size_t)(mt * 16 + l15) * 256 + h * 32 + qd * 8];
            acc_co[mt] = MFMA16(ao, bo, acc_co[mt]);
        }
    }

    // ---------------- epilogue: rows = co, cols = n -> coalesced stores ----
#pragma unroll
    for (int mt = 0; mt < 16; ++mt)
#pragma unroll
        for (int r = 0; r < 4; ++r) {
            int co = mt * 16 + qd * 4 + r;
            out[(size_t)(b * C_ + co) * N_ + n0 + wv * 16 + l15] = acc_co[mt][r] + o_b[co];
        }
}

// ---------------------------------------------------------------------------
extern "C" void kernel_launch(void* const* d_in, const int* in_sizes, int n_in,
                              void* d_out, int out_size, void* d_ws, size_t ws_size,
                              hipStream_t stream) {
    (void)in_sizes; (void)n_in; (void)out_size; (void)ws_size;
    const float* fv   = (const float*)d_in[0];
    const float* text = (const float*)d_in[1];
    const float* q_w  = (const float*)d_in[2];
    const float* q_b  = (const float*)d_in[3];
    const float* k_w  = (const float*)d_in[4];
    const float* k_b  = (const float*)d_in[5];
    const float* v_w  = (const float*)d_in[6];
    const float* v_b  = (const float*)d_in[7];
    const float* o_w  = (const float*)d_in[8];
    const float* o_b  = (const float*)d_in[9];
    const float* m1_w = (const float*)d_in[10];
    const float* m1_b = (const float*)d_in[11];
    const float* m2_w = (const float*)d_in[12];
    const float* m2_b = (const float*)d_in[13];
    float* out = (float*)d_out;

    short* wsS   = (short*)d_ws;
    short* k_rot = wsS;                      // 131072
    short* v_t   = wsS + 131072;             // 131072
    short* wt_q  = wsS + 262144;             // 65536
    short* wt_o  = wsS + 327680;             // 65536

    hipLaunchKernelGGL(prep_w, dim3(512), dim3(256), 0, stream, q_w, o_w, wt_q, wt_o);
    hipLaunchKernelGGL(text_stage, dim3(128), dim3(256), 0, stream,
                       text, k_w, k_b, v_w, v_b, m1_w, m1_b, m2_w, m2_b, k_rot, v_t);
    hipLaunchKernelGGL(fused_visual, dim3(512, 2), dim3(256), 0, stream,
                       fv, wt_q, q_b, k_rot, v_t, wt_o, o_b, out);
}